// Round 6
// baseline (2358.329 us; speedup 1.0000x reference)
//
#include <hip/hip_runtime.h>
#include <hip/hip_bf16.h>

// Problem dims
constexpr int NV   = 10000;  // vocab
constexpr int NE   = 512;    // embed
constexpr int NENC = 2048;   // encoder dim
constexpr int ND   = 512;    // decoder dim
constexpr int NA   = 512;    // attention dim
constexpr int NB   = 64;     // batch
constexpr int NL   = 49;     // locations
constexpr int NT   = 20;     // steps
constexpr int KX   = NE + NENC + ND;  // 3072 : x = [emb | context | h]
constexpr int KIH  = NE + NENC;       // 2560 : W_ih inner dim

typedef short bfrag __attribute__((ext_vector_type(8)));   // 8 bf16 (4 VGPRs)
typedef float f32x4 __attribute__((ext_vector_type(4)));   // MFMA acc

__device__ __forceinline__ float us2f(unsigned short u) {
    union { unsigned int i; float f; } x; x.i = (unsigned int)u << 16; return x.f;
}
__device__ __forceinline__ unsigned short f2us(float f) {  // RNE f32->bf16
    union { float f_; unsigned int u; } x; x.f_ = f;
    unsigned int r = (x.u + 0x7fffu + ((x.u >> 16) & 1u)) >> 16;
    return (unsigned short)r;
}

// ---------------------------------------------------------------------------
// K_mean: mean over L -> bf16. grid (B, NENC/256). Coalesced.
// ---------------------------------------------------------------------------
__launch_bounds__(256)
__global__ void k_mean(const float* __restrict__ enc, unsigned short* __restrict__ meanb)
{
    const int b = blockIdx.x;
    const int e = blockIdx.y * 256 + threadIdx.x;
    const float* p = enc + (size_t)b * NL * NENC + e;
    float s = 0.f;
    #pragma unroll 7
    for (int l = 0; l < NL; ++l) s += p[(size_t)l * NENC];
    meanb[(size_t)b * NENC + e] = f2us(s * (1.0f / NL));
}

// ---------------------------------------------------------------------------
// K_cvt: f32 -> bf16 flat copy (n multiple of 4).
// ---------------------------------------------------------------------------
__launch_bounds__(256)
__global__ void k_cvt(const float* __restrict__ src, unsigned short* __restrict__ dst, int n)
{
    int i = (blockIdx.x * 256 + threadIdx.x) * 4;
    if (i < n) {
        float4 v = *(const float4*)(src + i);
        dst[i + 0] = f2us(v.x); dst[i + 1] = f2us(v.y);
        dst[i + 2] = f2us(v.z); dst[i + 3] = f2us(v.w);
    }
}

// ---------------------------------------------------------------------------
// K_transpose: (K,N) f32 -> (N,K) bf16.  grid (ceil(N/32), K/32), 256 thr.
// ---------------------------------------------------------------------------
__launch_bounds__(256)
__global__ void k_transpose(const float* __restrict__ src, unsigned short* __restrict__ dst,
                            int K, int N)
{
    __shared__ float t[32][33];
    const int nb = blockIdx.x * 32, kb = blockIdx.y * 32;
    const int tx = threadIdx.x & 31, ty = threadIdx.x >> 5;  // ty 0..7
    #pragma unroll
    for (int i = ty; i < 32; i += 8) {
        int n = nb + tx;
        t[i][tx] = (n < N) ? src[(size_t)(kb + i) * N + n] : 0.f;
    }
    __syncthreads();
    #pragma unroll
    for (int i = ty; i < 32; i += 8) {
        int n = nb + i;
        if (n < N) dst[(size_t)n * K + kb + tx] = f2us(t[tx][i]);
    }
}

// ---------------------------------------------------------------------------
// K_init_mfma: [h|c](64,1024) = meanb(64,2048) @ WinitT(1024,2048)^T + bias.
// grid 64 n-tiles; 4 m-waves. h -> bf16, c -> f32.
// ---------------------------------------------------------------------------
__launch_bounds__(256)
__global__ void k_init_mfma(const unsigned short* __restrict__ meanb,
                            const unsigned short* __restrict__ WinitT,  // (1024,2048)
                            const float* __restrict__ bh, const float* __restrict__ bc,
                            unsigned short* __restrict__ hbf, float* __restrict__ c)
{
    const int wave = threadIdx.x >> 6, lane = threadIdx.x & 63;
    const int m0 = wave * 16, n0 = blockIdx.x * 16;
    const int r = lane & 15, quad = lane >> 4;
    const unsigned short* ap = meanb + (size_t)(m0 + r) * NENC + quad * 8;
    const unsigned short* bp = WinitT + (size_t)(n0 + r) * NENC + quad * 8;
    f32x4 acc = {0.f, 0.f, 0.f, 0.f};
    #pragma unroll 8
    for (int k = 0; k < NENC; k += 32) {
        bfrag a = *(const bfrag*)(ap + k);
        bfrag b = *(const bfrag*)(bp + k);
        acc = __builtin_amdgcn_mfma_f32_16x16x32_bf16(a, b, acc, 0, 0, 0);
    }
    const int col = n0 + r;
    const float bv = (col < ND) ? bh[col] : bc[col - ND];
    #pragma unroll
    for (int i = 0; i < 4; ++i) {
        int m = m0 + quad * 4 + i;
        float v = acc[i] + bv;
        if (col < ND) hbf[(size_t)m * ND + col] = f2us(v);
        else          c[(size_t)m * ND + col - ND] = v;
    }
}

// ---------------------------------------------------------------------------
// K_encproj_mfma: epb(3136,512)bf16 = encb(3136,2048) @ WeaT(512,2048)^T + bias
// ---------------------------------------------------------------------------
__launch_bounds__(256)
__global__ void k_encproj_mfma(const unsigned short* __restrict__ encb,
                               const unsigned short* __restrict__ WeaT,
                               const float* __restrict__ bias,
                               unsigned short* __restrict__ epb)
{
    const int wave = threadIdx.x >> 6, lane = threadIdx.x & 63;
    const int ntile = blockIdx.x & 31;
    const int mg    = blockIdx.x >> 5;             // 0..48
    const int m0 = (mg * 4 + wave) * 16;
    const int n0 = ntile * 16;
    const int r = lane & 15, quad = lane >> 4;
    const unsigned short* ap = encb + (size_t)(m0 + r) * NENC + quad * 8;
    const unsigned short* bp = WeaT + (size_t)(n0 + r) * NENC + quad * 8;
    f32x4 acc = {0.f, 0.f, 0.f, 0.f};
    #pragma unroll 8
    for (int k = 0; k < NENC; k += 32) {
        bfrag a = *(const bfrag*)(ap + k);
        bfrag b = *(const bfrag*)(bp + k);
        acc = __builtin_amdgcn_mfma_f32_16x16x32_bf16(a, b, acc, 0, 0, 0);
    }
    const float bv = bias[n0 + r];
    #pragma unroll
    for (int i = 0; i < 4; ++i) {
        int m = m0 + quad * 4 + i;
        epb[(size_t)m * NA + n0 + r] = f2us(acc[i] + bv);
    }
}

// ---------------------------------------------------------------------------
// K_decproj_mfma: dp(64,512)f32 = hbf(64,512) @ WdaT(512,512)^T + bda. grid 32.
// (used once in setup; per-step version is fused into k_out)
// ---------------------------------------------------------------------------
__launch_bounds__(256)
__global__ void k_decproj_mfma(const unsigned short* __restrict__ hbf,
                               const unsigned short* __restrict__ WdaT,
                               const float* __restrict__ bda,
                               float* __restrict__ dp)
{
    const int wave = threadIdx.x >> 6, lane = threadIdx.x & 63;
    const int m0 = wave * 16, n0 = blockIdx.x * 16;
    const int r = lane & 15, quad = lane >> 4;
    const unsigned short* ap = hbf + (size_t)(m0 + r) * ND + quad * 8;
    const unsigned short* bp = WdaT + (size_t)(n0 + r) * ND + quad * 8;
    f32x4 acc = {0.f, 0.f, 0.f, 0.f};
    #pragma unroll
    for (int k = 0; k < ND; k += 32) {
        bfrag a = *(const bfrag*)(ap + k);
        bfrag b = *(const bfrag*)(bp + k);
        acc = __builtin_amdgcn_mfma_f32_16x16x32_bf16(a, b, acc, 0, 0, 0);
    }
    const float bv = bda[n0 + r];
    #pragma unroll
    for (int i = 0; i < 4; ++i) {
        int m = m0 + quad * 4 + i;
        dp[(size_t)m * NA + n0 + r] = acc[i] + bv;
    }
}

// ---------------------------------------------------------------------------
// K_att: one block per b. scores=relu(ep+dp)@wf+b -> softmax -> alpha (f32 out)
// context from encb (bf16) -> x (bf16). Also x=[emb|context|h].
// ---------------------------------------------------------------------------
__launch_bounds__(256)
__global__ void k_att(int t,
                      const unsigned short* __restrict__ hbf,   // (B,D) bf16
                      const float* __restrict__ dpg,            // (B,A) f32
                      const unsigned short* __restrict__ epb,   // (B,L,A) bf16
                      const unsigned short* __restrict__ encb,  // (B,L,ENC) bf16
                      const float* __restrict__ wf,             // (A)
                      const float* __restrict__ bfs,            // scalar
                      const float* __restrict__ embt,           // (V,E) f32
                      const int* __restrict__ captions,         // (B,T)
                      unsigned short* __restrict__ x,           // (B,KX) bf16
                      float* __restrict__ alpha_out)            // (B,T,L) f32
{
    __shared__ float dp[NA];
    __shared__ float al[64];
    const int b = blockIdx.x, tid = threadIdx.x;

    for (int d = tid; d < ND; d += 256)
        x[(size_t)b * KX + NE + NENC + d] = hbf[(size_t)b * ND + d];  // h tail
    for (int a = tid; a < NA; a += 256)
        dp[a] = dpg[(size_t)b * NA + a];
    const int tok = captions[b * NT + t];
    for (int j = tid; j < NE; j += 256)
        x[(size_t)b * KX + j] = f2us(embt[(size_t)tok * NE + j]);
    __syncthreads();

    // scores: one wave per l
    const int wave = tid >> 6, lane = tid & 63;
    const float bfull = bfs[0];
    for (int l = wave; l < NL; l += 4) {
        const unsigned short* ep = epb + ((size_t)b * NL + l) * NA;
        float s = 0.f;
        #pragma unroll
        for (int a = lane; a < NA; a += 64) {
            float v = us2f(ep[a]) + dp[a];
            v = v > 0.f ? v : 0.f;
            s = fmaf(v, wf[a], s);
        }
        #pragma unroll
        for (int off = 32; off > 0; off >>= 1) s += __shfl_down(s, off, 64);
        if (lane == 0) al[l] = s + bfull;
    }
    __syncthreads();

    // softmax over L=49 (first wave)
    if (tid < 64) {
        float v = (tid < NL) ? al[tid] : -1e30f;
        float m = v;
        #pragma unroll
        for (int off = 32; off > 0; off >>= 1) m = fmaxf(m, __shfl_xor(m, off, 64));
        float e = (tid < NL) ? expf(v - m) : 0.f;
        float s = e;
        #pragma unroll
        for (int off = 32; off > 0; off >>= 1) s += __shfl_xor(s, off, 64);
        float a = e / s;
        if (tid < NL) {
            al[tid] = a;
            alpha_out[((size_t)b * NT + t) * NL + tid] = a;
        }
    }
    __syncthreads();

    // context -> x middle, bf16. thread covers 4 consecutive e, two passes.
    #pragma unroll
    for (int part = 0; part < 2; ++part) {
        const int e = part * 1024 + tid * 4;
        const unsigned short* p = encb + (size_t)b * NL * NENC + e;
        float s0 = 0.f, s1 = 0.f, s2 = 0.f, s3 = 0.f;
        #pragma unroll 7
        for (int l = 0; l < NL; ++l) {
            ushort4 v = *(const ushort4*)(p + (size_t)l * NENC);
            float a = al[l];
            s0 = fmaf(a, us2f(v.x), s0);
            s1 = fmaf(a, us2f(v.y), s1);
            s2 = fmaf(a, us2f(v.z), s2);
            s3 = fmaf(a, us2f(v.w), s3);
        }
        unsigned short* xo = x + (size_t)b * KX + NE + e;
        xo[0] = f2us(s0); xo[1] = f2us(s1); xo[2] = f2us(s2); xo[3] = f2us(s3);
    }
}

// ---------------------------------------------------------------------------
// K_gateslstm: fused gates GEMM + LSTM pointwise. grid 32 (16 d-cols each).
// Wave w computes gate w's 64x16 tile (2 m-tiles interleaved for ILP, twice).
// Epilogue through LDS applies i,f,g,o -> updates c (f32), h (bf16).
// ---------------------------------------------------------------------------
__launch_bounds__(256)
__global__ void k_gateslstm(const unsigned short* __restrict__ x,     // (64,3072)
                            const unsigned short* __restrict__ Wihb,  // (2048,2560)
                            const unsigned short* __restrict__ Whhb,  // (2048,512)
                            const float* __restrict__ bih, const float* __restrict__ bhh,
                            unsigned short* __restrict__ hbf, float* __restrict__ c)
{
    __shared__ float g[4][NB][16];   // 16 KB
    const int wave = threadIdx.x >> 6, lane = threadIdx.x & 63;
    const int r = lane & 15, quad = lane >> 4;
    const int n0 = blockIdx.x * 16;            // d-columns of this block
    const int ncol = wave * 512 + n0;          // column in 2048-wide gate space
    const unsigned short* bp1 = Wihb + (size_t)(ncol + r) * KIH + quad * 8;
    const unsigned short* bp2 = Whhb + (size_t)(ncol + r) * ND + quad * 8;
    #pragma unroll
    for (int half = 0; half < 2; ++half) {
        const int m0 = half * 32;
        const unsigned short* ap0 = x + (size_t)(m0 + r) * KX + quad * 8;
        const unsigned short* ap1 = x + (size_t)(m0 + 16 + r) * KX + quad * 8;
        f32x4 acc0 = {0.f, 0.f, 0.f, 0.f}, acc1 = {0.f, 0.f, 0.f, 0.f};
        #pragma unroll 4
        for (int k = 0; k < KIH; k += 32) {
            bfrag b  = *(const bfrag*)(bp1 + k);
            bfrag a0 = *(const bfrag*)(ap0 + k);
            bfrag a1 = *(const bfrag*)(ap1 + k);
            acc0 = __builtin_amdgcn_mfma_f32_16x16x32_bf16(a0, b, acc0, 0, 0, 0);
            acc1 = __builtin_amdgcn_mfma_f32_16x16x32_bf16(a1, b, acc1, 0, 0, 0);
        }
        #pragma unroll 4
        for (int k = 0; k < ND; k += 32) {
            bfrag b  = *(const bfrag*)(bp2 + k);
            bfrag a0 = *(const bfrag*)(ap0 + KIH + k);
            bfrag a1 = *(const bfrag*)(ap1 + KIH + k);
            acc0 = __builtin_amdgcn_mfma_f32_16x16x32_bf16(a0, b, acc0, 0, 0, 0);
            acc1 = __builtin_amdgcn_mfma_f32_16x16x32_bf16(a1, b, acc1, 0, 0, 0);
        }
        #pragma unroll
        for (int i = 0; i < 4; ++i) {
            g[wave][m0 + quad * 4 + i][r]      = acc0[i];
            g[wave][m0 + 16 + quad * 4 + i][r] = acc1[i];
        }
    }
    __syncthreads();
    #pragma unroll
    for (int e = 0; e < 4; ++e) {
        const int flat = threadIdx.x + 256 * e;   // 0..1023
        const int b = flat >> 4, dc = flat & 15;
        const int d = n0 + dc;
        float gi = g[0][b][dc] + bih[d]        + bhh[d];
        float gf = g[1][b][dc] + bih[d + 512]  + bhh[d + 512];
        float gg = g[2][b][dc] + bih[d + 1024] + bhh[d + 1024];
        float go = g[3][b][dc] + bih[d + 1536] + bhh[d + 1536];
        float i_ = 1.f / (1.f + expf(-gi));
        float f_ = 1.f / (1.f + expf(-gf));
        float g_ = tanhf(gg);
        float o_ = 1.f / (1.f + expf(-go));
        const size_t idx = (size_t)b * ND + d;
        float cn = f_ * c[idx] + i_ * g_;
        float hn = o_ * tanhf(cn);
        c[idx] = cn;
        hbf[idx] = f2us(hn);
    }
}

// ---------------------------------------------------------------------------
// K_out: fused logits (blocks 0..624) + next-step decproj (blocks 625..656).
// Both consume the freshly-updated hbf.
// ---------------------------------------------------------------------------
__launch_bounds__(256)
__global__ void k_out(int t,
                      const unsigned short* __restrict__ hbf,    // (64,512)
                      const unsigned short* __restrict__ WoutT,  // (10000,512)
                      const float* __restrict__ bout,
                      const unsigned short* __restrict__ WdaT,   // (512,512)
                      const float* __restrict__ bda,
                      float* __restrict__ out,                   // (B,T,V)
                      float* __restrict__ dp)                    // (B,A)
{
    const int wave = threadIdx.x >> 6, lane = threadIdx.x & 63;
    const int r = lane & 15, quad = lane >> 4;
    const int m0 = wave * 16;
    if (blockIdx.x < NV / 16) {
        const int n0 = blockIdx.x * 16;
        const unsigned short* ap = hbf + (size_t)(m0 + r) * ND + quad * 8;
        const unsigned short* bp = WoutT + (size_t)(n0 + r) * ND + quad * 8;
        f32x4 acc = {0.f, 0.f, 0.f, 0.f};
        #pragma unroll
        for (int k = 0; k < ND; k += 32) {
            bfrag a = *(const bfrag*)(ap + k);
            bfrag b = *(const bfrag*)(bp + k);
            acc = __builtin_amdgcn_mfma_f32_16x16x32_bf16(a, b, acc, 0, 0, 0);
        }
        const float bv = bout[n0 + r];
        #pragma unroll
        for (int i = 0; i < 4; ++i) {
            int m = m0 + quad * 4 + i;
            out[((size_t)m * NT + t) * NV + n0 + r] = acc[i] + bv;
        }
    } else {
        const int n0 = (blockIdx.x - NV / 16) * 16;
        const unsigned short* ap = hbf + (size_t)(m0 + r) * ND + quad * 8;
        const unsigned short* bp = WdaT + (size_t)(n0 + r) * ND + quad * 8;
        f32x4 acc = {0.f, 0.f, 0.f, 0.f};
        #pragma unroll
        for (int k = 0; k < ND; k += 32) {
            bfrag a = *(const bfrag*)(ap + k);
            bfrag b = *(const bfrag*)(bp + k);
            acc = __builtin_amdgcn_mfma_f32_16x16x32_bf16(a, b, acc, 0, 0, 0);
        }
        const float bv = bda[n0 + r];
        #pragma unroll
        for (int i = 0; i < 4; ++i) {
            int m = m0 + quad * 4 + i;
            dp[(size_t)m * NA + n0 + r] = acc[i] + bv;
        }
    }
}

// ---------------------------------------------------------------------------
extern "C" void kernel_launch(void* const* d_in, const int* in_sizes, int n_in,
                              void* d_out, int out_size, void* d_ws, size_t ws_size,
                              hipStream_t stream) {
    const float* enc  = (const float*)d_in[0];
    const int*   caps = (const int*)d_in[1];
    const float* embt = (const float*)d_in[2];
    const float* Wea  = (const float*)d_in[3];
    const float* bea  = (const float*)d_in[4];
    const float* Wda  = (const float*)d_in[5];
    const float* bda  = (const float*)d_in[6];
    const float* wf   = (const float*)d_in[7];
    const float* bfs  = (const float*)d_in[8];
    const float* Wih  = (const float*)d_in[9];
    const float* bih  = (const float*)d_in[10];
    const float* Whh  = (const float*)d_in[11];
    const float* bhh  = (const float*)d_in[12];
    const float* Wh0  = (const float*)d_in[13];
    const float* bh0  = (const float*)d_in[14];
    const float* Wc0  = (const float*)d_in[15];
    const float* bc0  = (const float*)d_in[16];
    const float* Wout = (const float*)d_in[17];
    const float* bout = (const float*)d_in[18];

    float* out = (float*)d_out;                       // logits (B,T,V) f32
    float* alpha_out = out + (size_t)NB * NT * NV;    // alphas (B,T,L) f32

    // ---- workspace carve-up (16B aligned) ----
    char* w = (char*)d_ws;
    float* c  = (float*)w;                      w += (size_t)NB * ND * 4;          // 128 KB
    float* dp = (float*)w;                      w += (size_t)NB * NA * 4;          // 128 KB
    unsigned short* hbf   = (unsigned short*)w; w += (size_t)NB * ND * 2;          // 64 KB
    unsigned short* x     = (unsigned short*)w; w += (size_t)NB * KX * 2;          // 384 KB
    unsigned short* meanb = (unsigned short*)w; w += (size_t)NB * NENC * 2;        // 256 KB
    unsigned short* epb   = (unsigned short*)w; w += (size_t)NB * NL * NA * 2;     // 3.2 MB
    unsigned short* encb  = (unsigned short*)w; w += (size_t)NB * NL * NENC * 2;   // 12.8 MB
    unsigned short* Wihb  = (unsigned short*)w; w += (size_t)4 * ND * KIH * 2;     // 10.5 MB
    unsigned short* Whhb  = (unsigned short*)w; w += (size_t)4 * ND * ND * 2;      // 2 MB
    unsigned short* WeaT  = (unsigned short*)w; w += (size_t)NA * NENC * 2;        // 2 MB
    unsigned short* WdaT  = (unsigned short*)w; w += (size_t)NA * ND * 2;          // 0.5 MB
    // WinitT (1024x2048 bf16 = 4 MB) aliases the WoutT region (10000x512 bf16 =
    // 10.2 MB): WinitT is consumed by k_init_mfma BEFORE Wout's transpose runs.
    unsigned short* Wunion = (unsigned short*)w;  // max(4 MB, 10.2 MB)
    unsigned short* WinitT = Wunion;
    unsigned short* WoutT  = Wunion;

    // ---- one-time setup ----
    hipLaunchKernelGGL(k_mean, dim3(NB, NENC / 256), dim3(256), 0, stream, enc, meanb);
    hipLaunchKernelGGL(k_transpose, dim3(ND / 32, NENC / 32), dim3(256), 0, stream,
                       Wh0, WinitT, NENC, ND);
    hipLaunchKernelGGL(k_transpose, dim3(ND / 32, NENC / 32), dim3(256), 0, stream,
                       Wc0, WinitT + (size_t)ND * NENC, NENC, ND);
    hipLaunchKernelGGL(k_init_mfma, dim3(2 * ND / 16), dim3(256), 0, stream,
                       meanb, WinitT, bh0, bc0, hbf, c);
    {
        int n = NB * NL * NENC;
        hipLaunchKernelGGL(k_cvt, dim3(n / 4 / 256), dim3(256), 0, stream, enc, encb, n);
    }
    {
        int n = 4 * ND * KIH;
        hipLaunchKernelGGL(k_cvt, dim3(n / 4 / 256), dim3(256), 0, stream, Wih, Wihb, n);
    }
    {
        int n = 4 * ND * ND;
        hipLaunchKernelGGL(k_cvt, dim3(n / 4 / 256), dim3(256), 0, stream, Whh, Whhb, n);
    }
    hipLaunchKernelGGL(k_transpose, dim3(NA / 32, NENC / 32), dim3(256), 0, stream,
                       Wea, WeaT, NENC, NA);
    hipLaunchKernelGGL(k_transpose, dim3(NA / 32, ND / 32), dim3(256), 0, stream,
                       Wda, WdaT, ND, NA);
    hipLaunchKernelGGL(k_transpose, dim3((NV + 31) / 32, ND / 32), dim3(256), 0, stream,
                       Wout, WoutT, ND, NV);   // overwrites WinitT region (done with it)
    hipLaunchKernelGGL(k_encproj_mfma, dim3((NB * NL / 64) * (NA / 16)), dim3(256), 0, stream,
                       encb, WeaT, bea, epb);
    hipLaunchKernelGGL(k_decproj_mfma, dim3(NA / 16), dim3(256), 0, stream,
                       hbf, WdaT, bda, dp);    // dp for step 0

    // ---- 20 sequential decoder steps: 3 kernels each ----
    for (int t = 0; t < NT; ++t) {
        hipLaunchKernelGGL(k_att, dim3(NB), dim3(256), 0, stream,
                           t, hbf, dp, epb, encb, wf, bfs, embt, caps, x, alpha_out);
        hipLaunchKernelGGL(k_gateslstm, dim3(4 * ND / 16 / 4), dim3(256), 0, stream,
                           x, Wihb, Whhb, bih, bhh, hbf, c);
        hipLaunchKernelGGL(k_out, dim3(NV / 16 + NA / 16), dim3(256), 0, stream,
                           t, hbf, WoutT, bout, WdaT, bda, out, dp);
    }
}